// Round 15
// baseline (1340.104 us; speedup 1.0000x reference)
//
#include <hip/hip_runtime.h>
#include <stdint.h>
#include <stddef.h>

#define BB 8
#define NN 4096
#define MTOK 1024
#define DD 1024
#define HH 16
#define EPSF 1e-6f
static const float SCALE_F = 0.125f; // HD^-0.5, HD=64

typedef __attribute__((ext_vector_type(4))) float f32x4;
typedef __attribute__((ext_vector_type(8))) short bf16x8;

__device__ __forceinline__ short f2bf(float f) {
  union { float f; uint32_t u; } x; x.f = f;
  uint32_t r = (x.u + 0x7fffu + ((x.u >> 16) & 1u)) >> 16;
  return (short)(uint16_t)r;
}
__device__ __forceinline__ float bf2f(short s) {
  union { uint32_t u; float f; } x; x.u = ((uint32_t)(uint16_t)s) << 16;
  return x.f;
}

#if defined(__HIP_DEVICE_COMPILE__) && __has_builtin(__builtin_amdgcn_global_load_lds)
#define USE_GLOAD_LDS 1
#else
#define USE_GLOAD_LDS 0
#endif

#define BAR() __builtin_amdgcn_s_barrier()
#define LGKM0() asm volatile("s_waitcnt lgkmcnt(0)" ::: "memory")
#if USE_GLOAD_LDS
#define VMW6() asm volatile("s_waitcnt vmcnt(6)" ::: "memory")
#else
#define VMW6() asm volatile("s_waitcnt vmcnt(0) lgkmcnt(0)" ::: "memory")
#endif
#define VMW0() asm volatile("s_waitcnt vmcnt(0)" ::: "memory")

// ---------------------------------------------------------------------------
// 256x256 8-phase bf16 GEMM, read-ahead pipelined (minimal diff from the
// round-12 proven loop): reads for phase p+1 issue inside phase p AFTER its
// lgkm0, so they drain under phase p's MFMA + barrier. Phase start lgkm0
// certifies last phase's reads complete -> ONE barrier per phase is enough
// for stage safety. vmcnt(6) at P4/P8 before that phase's buf-switch reads.
// Register plan: a0(MH0), a1(MH1), b0(NH0), b1(NH1) — every read target is
// dead at its write phase (quadrant order 00,01,10,11 per tile).
// EPI: 0 f32 | 1 f32 + f32-resid | 2 bf16 | 3 bf16 silu
//      4 bf16 + f32-resid | 5 f32 + bf16-resid
// ---------------------------------------------------------------------------
__device__ __forceinline__ bf16x8 ldsld(const char* p, int off) {
  return *(const bf16x8*)(p + off);
}
template <int MH>
__device__ __forceinline__ void rdA8(const char* k0, const char* k1, bf16x8 a[4][2]) {
#pragma unroll
  for (int m = 0; m < 4; ++m) {
    a[m][0] = ldsld(k0, MH * 8192 + m * 2048);
    a[m][1] = ldsld(k1, MH * 8192 + m * 2048);
  }
}
template <int NH>
__device__ __forceinline__ void rdB4(const char* k0, const char* k1, bf16x8 b[2][2]) {
#pragma unroll
  for (int n = 0; n < 2; ++n) {
    b[n][0] = ldsld(k0, NH * 16384 + n * 2048);
    b[n][1] = ldsld(k1, NH * 16384 + n * 2048);
  }
}
__device__ __forceinline__ void stgA(char* smc, int base, const short* pg,
                                     int ld, int mh, int k, int w) {
#pragma unroll
  for (int i = 0; i < 2; ++i) {
    const short* src = pg + (long)(mh * 64 + i * 128) * ld + k;
    char* dst = smc + base + i * 16384 + mh * 8192 + w * 1024;
#if USE_GLOAD_LDS
    __builtin_amdgcn_global_load_lds(
        (const __attribute__((address_space(1))) void*)src,
        (__attribute__((address_space(3))) void*)dst, 16, 0, 0);
#else
    *(bf16x8*)(dst + (int)(threadIdx.x & 63) * 16) = *(const bf16x8*)src;
#endif
  }
}
__device__ __forceinline__ void stgB(char* smc, int base, const short* pg,
                                     int ld, int h, int k, int w) {
#pragma unroll
  for (int i = 0; i < 2; ++i) {
    const short* src = pg + (long)(h * 32 + i * 128) * ld + k;
    char* dst = smc + base + h * 16384 + i * 8192 + w * 1024;
#if USE_GLOAD_LDS
    __builtin_amdgcn_global_load_lds(
        (const __attribute__((address_space(1))) void*)src,
        (__attribute__((address_space(3))) void*)dst, 16, 0, 0);
#else
    *(bf16x8*)(dst + (int)(threadIdx.x & 63) * 16) = *(const bf16x8*)src;
#endif
  }
}
template <int MH, int NH>
__device__ __forceinline__ void mq(const bf16x8 a[4][2], const bf16x8 b[2][2],
                                   f32x4 acc[8][4]) {
  __builtin_amdgcn_s_setprio(1);
#pragma unroll
  for (int m = 0; m < 4; ++m)
#pragma unroll
    for (int n = 0; n < 2; ++n) {
      f32x4 c = acc[MH * 4 + m][NH * 2 + n];
      c = __builtin_amdgcn_mfma_f32_16x16x32_bf16(a[m][0], b[n][0], c, 0, 0, 0);
      c = __builtin_amdgcn_mfma_f32_16x16x32_bf16(a[m][1], b[n][1], c, 0, 0, 0);
      acc[MH * 4 + m][NH * 2 + n] = c;
    }
  __builtin_amdgcn_s_setprio(0);
}

template <int EPI>
__global__ __launch_bounds__(512, 2) void gemm256(
    const short* __restrict__ A, const short* __restrict__ BT,
    const float* __restrict__ bias, const void* __restrict__ resid,
    void* __restrict__ outp, int N, int K, int lda, int ldb, int num_n) {
  __shared__ int4 smem4[131072 / 16];
  char* smc = (char*)smem4;
  const int t = threadIdx.x;
  const int w = t >> 6, lane = t & 63;
  const int wr = w >> 2, wc = w & 3;

  // bijective XCD swizzle (m204)
  const int nwg = gridDim.x, orig = blockIdx.x;
  const int q8 = nwg >> 3, r8 = nwg & 7;
  const int xcd = orig & 7, loc = orig >> 3;
  const int wg = (xcd < r8 ? xcd * (q8 + 1) : r8 * (q8 + 1) + (xcd - r8) * q8) + loc;
  // ROW-major tile mapping: consecutive wg (same XCD) share the A panel.
  const int bm = wg / num_n, bn = wg % num_n;

  const int T = K >> 6;

  // swizzled ds_read base pointers (ks=1 = base^64)
  int LA = wr * 16384 + (lane & 15) * 128 + ((lane >> 4) << 4);
  LA ^= ((LA >> 7) & 7) << 4;
  int LB = wc * 4096 + (lane & 15) * 128 + ((lane >> 4) << 4);
  LB ^= ((LB >> 7) & 7) << 4;
  const char* pA0k0 = smc + LA;
  const char* pA0k1 = smc + (LA ^ 64);
  const char* pA1k0 = pA0k0 + 65536;
  const char* pA1k1 = pA0k1 + 65536;
  const char* pB0k0 = smc + 32768 + LB;
  const char* pB0k1 = smc + 32768 + (LB ^ 64);
  const char* pB1k0 = pB0k0 + 65536;
  const char* pB1k1 = pB0k1 + 65536;

  // stage source pointers (pre-swizzled per-thread row/col)
  const int colswz = ((t & 7) ^ ((t >> 3) & 7)) * 8;
  const short* pAg = A + (long)(bm * 256 + (t >> 3)) * lda + colswz;
  const short* pBg =
      BT + (long)(bn * 256 + ((t >> 8) * 64 + ((t >> 3) & 31))) * ldb + colswz;

  f32x4 acc[8][4];
#pragma unroll
  for (int i = 0; i < 8; ++i)
#pragma unroll
    for (int j = 0; j < 4; ++j) acc[i][j] = (f32x4){0.f, 0.f, 0.f, 0.f};

  bf16x8 a0[4][2], a1[4][2], b0[2][2], b1[2][2];

  // ---- prologue: buf0 <- tile0 (4 halves), buf1 <- tile1 (A0,B0,B1)
  stgA(smc, 0, pAg, lda, 0, 0, w);
  stgB(smc, 32768, pBg, ldb, 0, 0, w);
  stgB(smc, 32768, pBg, ldb, 1, 0, w);
  stgA(smc, 0, pAg, lda, 1, 0, w);
  stgA(smc, 65536, pAg, lda, 0, 64, w);
  stgB(smc, 98304, pBg, ldb, 0, 64, w);
  stgB(smc, 98304, pBg, ldb, 1, 64, w);
  VMW6();
  BAR();
  // issue P1's reads (tile0 A-MH0, B-NH0)
  rdA8<0>(pA0k0, pA0k1, a0);
  rdB4<0>(pB0k0, pB0k1, b0);

  for (int t2 = 0; t2 < T; t2 += 2) {
    const int k1 = (t2 + 1) * 64;
    const int k2 = (t2 + 2 < T ? t2 + 2 : 0) * 64;
    const int k3 = (t2 + 3 < T ? t2 + 3 : 0) * 64;
    // P1: wait(a0,b0) | rd b1 (P2) | st buf1.A1<-t2+1 | MFMA(00)
    LGKM0();
    rdB4<1>(pB0k0, pB0k1, b1);
    stgA(smc, 65536, pAg, lda, 1, k1, w);
    mq<0, 0>(a0, b0, acc);
    BAR();
    // P2: wait(b1) | rd a1 (P3) | st buf0.A0<-t2+2 | MFMA(01)
    LGKM0();
    rdA8<1>(pA0k0, pA0k1, a1);
    stgA(smc, 0, pAg, lda, 0, k2, w);
    mq<0, 1>(a0, b1, acc);
    BAR();
    // P3: wait(a1) | st buf0.B0<-t2+2 | MFMA(10)
    LGKM0();
    stgB(smc, 32768, pBg, ldb, 0, k2, w);
    mq<1, 0>(a1, b0, acc);
    BAR();
    // P4: vmcnt(6) | rd buf1 a0,b0 (P5) | st buf0.B1<-t2+2 | MFMA(11)
    LGKM0();
    VMW6();
    rdA8<0>(pA1k0, pA1k1, a0);
    rdB4<0>(pB1k0, pB1k1, b0);
    stgB(smc, 32768, pBg, ldb, 1, k2, w);
    mq<1, 1>(a1, b1, acc);
    BAR();
    // P5: wait(a0,b0) | rd b1 (P6) | st buf0.A1<-t2+2 | MFMA(00)
    LGKM0();
    rdB4<1>(pB1k0, pB1k1, b1);
    stgA(smc, 0, pAg, lda, 1, k2, w);
    mq<0, 0>(a0, b0, acc);
    BAR();
    // P6: wait(b1) | rd a1 (P7) | st buf1.A0<-t2+3 | MFMA(01)
    LGKM0();
    rdA8<1>(pA1k0, pA1k1, a1);
    stgA(smc, 65536, pAg, lda, 0, k3, w);
    mq<0, 1>(a0, b1, acc);
    BAR();
    // P7: wait(a1) | st buf1.B0<-t2+3 | MFMA(10)
    LGKM0();
    stgB(smc, 98304, pBg, ldb, 0, k3, w);
    mq<1, 0>(a1, b0, acc);
    BAR();
    // P8: vmcnt(6) | rd buf0 a0,b0 (next P1) | st buf1.B1<-t2+3 | MFMA(11)
    LGKM0();
    VMW6();
    rdA8<0>(pA0k0, pA0k1, a0);
    rdB4<0>(pB0k0, pB0k1, b0);
    stgB(smc, 98304, pBg, ldb, 1, k3, w);
    mq<1, 1>(a1, b1, acc);
    BAR();
  }
  LGKM0();
  VMW0();

  // ---- epilogue ----
  const int r0 = bm * 256 + wr * 128 + ((lane >> 4) << 2);
  const int c0 = bn * 256 + wc * 64 + (lane & 15);
#pragma unroll
  for (int mi = 0; mi < 8; ++mi) {
#pragma unroll
    for (int ni = 0; ni < 4; ++ni) {
      const int col = c0 + ni * 16;
      const float bv = bias ? bias[col] : 0.f;
#pragma unroll
      for (int rr = 0; rr < 4; ++rr) {
        const int row = r0 + mi * 16 + rr;
        const long idx = (long)row * N + col;
        float v = acc[mi][ni][rr] + bv;
        if (EPI == 0) {
          ((float*)outp)[idx] = v;
        } else if (EPI == 1) {
          ((float*)outp)[idx] = v + ((const float*)resid)[idx];
        } else if (EPI == 2) {
          ((short*)outp)[idx] = f2bf(v);
        } else if (EPI == 3) {
          v = v / (1.f + __expf(-v));
          ((short*)outp)[idx] = f2bf(v);
        } else if (EPI == 4) {
          ((short*)outp)[idx] = f2bf(v + ((const float*)resid)[idx]);
        } else {
          ((float*)outp)[idx] = v + bf2f(((const short*)resid)[idx]);
        }
      }
    }
  }
}

// ---------------------------------------------------------------------------
// Row LayerNorm over D=1024, fp32 in -> bf16 out. One block (256 thr) per row.
// ---------------------------------------------------------------------------
__global__ __launch_bounds__(256) void ln_rows(const float* __restrict__ in,
                                               const float* __restrict__ g,
                                               const float* __restrict__ bta,
                                               short* __restrict__ outp) {
  const int row = blockIdx.x;
  const int t = threadIdx.x;
  const float4 v = ((const float4*)(in + (long)row * DD))[t];
  float s = v.x + v.y + v.z + v.w;
  float ss = v.x * v.x + v.y * v.y + v.z * v.z + v.w * v.w;
#pragma unroll
  for (int off = 1; off < 64; off <<= 1) {
    s += __shfl_xor(s, off);
    ss += __shfl_xor(ss, off);
  }
  __shared__ float red[8];
  const int w = t >> 6, lane = t & 63;
  if (lane == 0) { red[w] = s; red[4 + w] = ss; }
  __syncthreads();
  s = red[0] + red[1] + red[2] + red[3];
  ss = red[4] + red[5] + red[6] + red[7];
  const float mu = s * (1.f / DD);
  const float var = ss * (1.f / DD) - mu * mu;
  const float rs = rsqrtf(var + EPSF);
  const float4 gv = ((const float4*)g)[t];
  const float4 bv = ((const float4*)bta)[t];
  short4 o;
  o.x = f2bf((v.x - mu) * rs * gv.x + bv.x);
  o.y = f2bf((v.y - mu) * rs * gv.y + bv.y);
  o.z = f2bf((v.z - mu) * rs * gv.z + bv.z);
  o.w = f2bf((v.w - mu) * rs * gv.w + bv.w);
  ((short4*)(outp + (long)row * DD))[t] = o;
}

// ---------------------------------------------------------------------------
// Row LayerNorm, bf16 in -> bf16 out (for x2).
// ---------------------------------------------------------------------------
__global__ __launch_bounds__(256) void ln_rows_b(const short* __restrict__ in,
                                                 const float* __restrict__ g,
                                                 const float* __restrict__ bta,
                                                 short* __restrict__ outp) {
  const int row = blockIdx.x;
  const int t = threadIdx.x;
  const short4 v4 = ((const short4*)(in + (long)row * DD))[t];
  const float v0 = bf2f(v4.x), v1 = bf2f(v4.y), v2 = bf2f(v4.z), v3 = bf2f(v4.w);
  float s = v0 + v1 + v2 + v3;
  float ss = v0 * v0 + v1 * v1 + v2 * v2 + v3 * v3;
#pragma unroll
  for (int off = 1; off < 64; off <<= 1) {
    s += __shfl_xor(s, off);
    ss += __shfl_xor(ss, off);
  }
  __shared__ float red[8];
  const int w = t >> 6, lane = t & 63;
  if (lane == 0) { red[w] = s; red[4 + w] = ss; }
  __syncthreads();
  s = red[0] + red[1] + red[2] + red[3];
  ss = red[4] + red[5] + red[6] + red[7];
  const float mu = s * (1.f / DD);
  const float var = ss * (1.f / DD) - mu * mu;
  const float rs = rsqrtf(var + EPSF);
  const float4 gv = ((const float4*)g)[t];
  const float4 bv = ((const float4*)bta)[t];
  short4 o;
  o.x = f2bf((v0 - mu) * rs * gv.x + bv.x);
  o.y = f2bf((v1 - mu) * rs * gv.y + bv.y);
  o.z = f2bf((v2 - mu) * rs * gv.z + bv.z);
  o.w = f2bf((v3 - mu) * rs * gv.w + bv.w);
  ((short4*)(outp + (long)row * DD))[t] = o;
}

// ---------------------------------------------------------------------------
// Transpose + fp32->bf16 convert: W[K][N] -> WT[N][K]. 64x64 tiles.
// ---------------------------------------------------------------------------
__global__ __launch_bounds__(256) void tconv(const float* __restrict__ W,
                                             short* __restrict__ WT, int K, int N) {
  __shared__ float tile[64][65];
  const int k0 = blockIdx.x * 64, n0 = blockIdx.y * 64;
  const int t = threadIdx.x;
  const int tr = t >> 6, tc = t & 63;
#pragma unroll
  for (int i = 0; i < 64; i += 4)
    tile[i + tr][tc] = W[(long)(k0 + i + tr) * N + n0 + tc];
  __syncthreads();
#pragma unroll
  for (int i = 0; i < 64; i += 4)
    WT[(long)(n0 + i + tr) * K + k0 + tc] = f2bf(tile[tc][i + tr]);
}

// ---------------------------------------------------------------------------
// ctx[b,h,d,e] = sum_m softmax_d(k[b,m,h,:])[d] * v[b,m,h,e].
// ---------------------------------------------------------------------------
__global__ __launch_bounds__(256) void ctx_kernel(const short* __restrict__ kv,
                                                  float* __restrict__ ctx) {
  const int bh = blockIdx.x;
  const int b = bh >> 4, h = bh & 15;
  const int t = threadIdx.x, g = t >> 6, lane = t & 63;
  __shared__ float ksm[4][64];
  __shared__ float vsm[4][64];
  float acc[16];
#pragma unroll
  for (int j = 0; j < 16; ++j) acc[j] = 0.f;
  const int d = t & 63;
  const int e0 = (t >> 6) * 16;
  const short* base = kv + (long)b * MTOK * 2048 + h * 64;
  for (int m0 = 0; m0 < MTOK; m0 += 4) {
    const long moff = (long)(m0 + g) * 2048;
    float kval = bf2f(base[moff + lane]);
    float vval = bf2f(base[moff + 1024 + lane]);
    float mx = kval;
#pragma unroll
    for (int off = 1; off < 64; off <<= 1) mx = fmaxf(mx, __shfl_xor(mx, off));
    float e = __expf(kval - mx);
    float sm = e;
#pragma unroll
    for (int off = 1; off < 64; off <<= 1) sm += __shfl_xor(sm, off);
    ksm[g][lane] = e / sm;
    vsm[g][lane] = vval;
    __syncthreads();
#pragma unroll
    for (int mm = 0; mm < 4; ++mm) {
      const float kd = ksm[mm][d];
#pragma unroll
      for (int j = 0; j < 16; ++j) acc[j] = fmaf(kd, vsm[mm][e0 + j], acc[j]);
    }
    __syncthreads();
  }
  float* cp = ctx + ((long)bh * 64 + d) * 64 + e0;
#pragma unroll
  for (int j = 0; j < 16; ++j) cp[j] = acc[j];
}

// ---------------------------------------------------------------------------
// Column softmax stats for q (bf16), softmax over the N axis per (b, column).
// ---------------------------------------------------------------------------
__global__ __launch_bounds__(256) void qstat_part(const short* __restrict__ q,
                                                  float* __restrict__ pmax,
                                                  float* __restrict__ psum) {
  const int c = blockIdx.x * 256 + threadIdx.x;
  const int b = blockIdx.z, ch = blockIdx.y;
  const short* qp = q + ((long)b * NN + ch * 128) * DD + c;
  float mx = -1e30f, sm = 0.f;
  for (int r = 0; r < 128; ++r) {
    const float xv = bf2f(qp[(long)r * DD]);
    const float nm = fmaxf(mx, xv);
    sm = sm * __expf(mx - nm) + __expf(xv - nm);
    mx = nm;
  }
  const long idx = ((long)b * DD + c) * 32 + ch;
  pmax[idx] = mx;
  psum[idx] = sm;
}

__global__ __launch_bounds__(256) void qstat_comb(const float* __restrict__ pmax,
                                                  const float* __restrict__ psum,
                                                  float* __restrict__ cmax,
                                                  float* __restrict__ crs) {
  const int i = blockIdx.x * 256 + threadIdx.x;  // b*1024 + c
  const float* pm = pmax + (long)i * 32;
  const float* ps = psum + (long)i * 32;
  float mx = -1e30f;
#pragma unroll
  for (int ch = 0; ch < 32; ++ch) mx = fmaxf(mx, pm[ch]);
  float sm = 0.f;
#pragma unroll
  for (int ch = 0; ch < 32; ++ch) sm += ps[ch] * __expf(pm[ch] - mx);
  cmax[i] = mx;
  crs[i] = SCALE_F / sm;
}

// ---------------------------------------------------------------------------
// Fused: q_soft = exp(q-cmax)*crs (includes SCALE), out = q_soft @ ctx[b,h].
// q is bf16.
// ---------------------------------------------------------------------------
__global__ __launch_bounds__(256) void attn_apply(const short* __restrict__ q,
                                                  const float* __restrict__ ctx,
                                                  const float* __restrict__ cmax,
                                                  const float* __restrict__ crs,
                                                  short* __restrict__ outa) {
  const int b = blockIdx.z, h = blockIdx.y, n0 = blockIdx.x * 128;
  const int t = threadIdx.x, g = t >> 6, lane = t & 63;
  __shared__ float ctx_l[4096];
  __shared__ float cm[64], cs[64];
  __shared__ float qsm[4][64];
  const float* cp = ctx + (long)(b * HH + h) * 4096;
  for (int i = t; i < 4096; i += 256) ctx_l[i] = cp[i];
  if (t < 64) {
    cm[t] = cmax[(long)b * DD + h * 64 + t];
    cs[t] = crs[(long)b * DD + h * 64 + t];
  }
  __syncthreads();
  for (int i = 0; i < 32; ++i) {
    const int n = n0 + i * 4 + g;
    const long off = ((long)b * NN + n) * DD + h * 64;
    const float qv = bf2f(q[off + lane]);
    const float qs = __expf(qv - cm[lane]) * cs[lane];
    qsm[g][lane] = qs;  // same-wave LDS, no barrier needed
    float o = 0.f;
#pragma unroll
    for (int dd = 0; dd < 64; ++dd) o = fmaf(qsm[g][dd], ctx_l[dd * 64 + lane], o);
    outa[off + lane] = f2bf(o);
  }
}

// ---------------------------------------------------------------------------
extern "C" void kernel_launch(void* const* d_in, const int* in_sizes, int n_in,
                              void* d_out, int out_size, void* d_ws, size_t ws_size,
                              hipStream_t stream) {
  (void)in_sizes; (void)n_in; (void)out_size;
  const float* x      = (const float*)d_in[0];
  const float* wav    = (const float*)d_in[1];
  const float* ln_q_g = (const float*)d_in[2];
  const float* ln_q_b = (const float*)d_in[3];
  const float* Wq     = (const float*)d_in[4];
  const float* bq     = (const float*)d_in[5];
  const float* ln_kv_g= (const float*)d_in[6];
  const float* ln_kv_b= (const float*)d_in[7];
  const float* Wkv    = (const float*)d_in[8];
  const float* bkv    = (const float*)d_in[9];
  const float* Wo     = (const float*)d_in[10];
  const float* bo     = (const float*)d_in[11];
  const float* ln_f_g = (const float*)d_in[12];
  const float* ln_f_b = (const float*)d_in[13];
  const float* W1     = (const float*)d_in[14];
  const float* b1     = (const float*)d_in[15];
  const float* W2     = (const float*)d_in[16];
  const float* b2     = (const float*)d_in[17];
  float* outp = (float*)d_out;
  char* ws = (char*)d_ws;

  const long MR = (long)BB * NN;    // 32768 rows
  const long MKV = (long)BB * MTOK; // 8192 rows

  size_t off = 0;
  auto bump = [&](size_t bytes) {
    size_t o = off;
    off += (bytes + 255) & ~(size_t)255;
    return o;
  };
  short* WqT  = (short*)(ws + bump((size_t)DD * DD * 2));
  short* WkvT = (short*)(ws + bump((size_t)2048 * DD * 2));
  short* WoT  = (short*)(ws + bump((size_t)DD * DD * 2));
  short* W1T  = (short*)(ws + bump((size_t)4096 * DD * 2));
  short* W2T  = (short*)(ws + bump((size_t)DD * 4096 * 2));
  short* qbuf = (short*)(ws + bump((size_t)MR * DD * 2));   // q bf16, later x2 bf16
  short* lnbuf= (short*)(ws + bump((size_t)MR * DD * 2));   // xq_ln, later x2_ln
  float* ctx  = (float*)(ws + bump((size_t)BB * HH * 64 * 64 * 4));
  float* pmax = (float*)(ws + bump((size_t)BB * DD * 32 * 4));
  float* psum = (float*)(ws + bump((size_t)BB * DD * 32 * 4));
  float* cmax = (float*)(ws + bump((size_t)BB * DD * 4));
  float* crs  = (float*)(ws + bump((size_t)BB * DD * 4));
  const size_t dyn0 = off;
  short* wvln  = (short*)(ws + dyn0);
  short* kvbuf = (short*)(ws + dyn0 + (size_t)MKV * DD * 2);
  short* oattn = (short*)(ws + dyn0);  // reuses wvln+kv region (dead by then)
  short* hbuf  = (short*)(ws + dyn0);  // MLP phase (oattn dead by then)

  size_t avail = ws_size > dyn0 ? ws_size - dyn0 : 0;
  int CS = 4096;
  while (CS > 256 && (size_t)MR * CS * 2 > avail) CS >>= 1;

  const int nm = (int)(MR / 256);    // 128
  const int nmkv = (int)(MKV / 256); // 32

  // 1) weight convert+transpose to bf16 [N][K]
  tconv<<<dim3(DD / 64, DD / 64), 256, 0, stream>>>(Wq, WqT, DD, DD);
  tconv<<<dim3(DD / 64, 2048 / 64), 256, 0, stream>>>(Wkv, WkvT, DD, 2048);
  tconv<<<dim3(DD / 64, DD / 64), 256, 0, stream>>>(Wo, WoT, DD, DD);
  tconv<<<dim3(DD / 64, 4096 / 64), 256, 0, stream>>>(W1, W1T, DD, 4096);
  tconv<<<dim3(4096 / 64, DD / 64), 256, 0, stream>>>(W2, W2T, 4096, DD);

  // 2) LayerNorms -> bf16
  ln_rows<<<dim3((unsigned)MR), 256, 0, stream>>>(x, ln_q_g, ln_q_b, lnbuf);
  ln_rows<<<dim3((unsigned)MKV), 256, 0, stream>>>(wav, ln_kv_g, ln_kv_b, wvln);

  // 3) q = LN(x) @ Wq + bq   -> bf16
  gemm256<2><<<dim3((unsigned)(nm * (DD / 256))), 512, 0, stream>>>(
      lnbuf, WqT, bq, nullptr, qbuf, DD, DD, DD, DD, DD / 256);
  // 4) kv = LN(wav) @ Wkv + bkv  (bf16 out)
  gemm256<2><<<dim3((unsigned)(nmkv * (2048 / 256))), 512, 0, stream>>>(
      wvln, WkvT, bkv, nullptr, kvbuf, 2048, DD, DD, DD, 2048 / 256);
  // 5) context per (b,h)
  ctx_kernel<<<dim3(BB * HH), 256, 0, stream>>>(kvbuf, ctx);
  // 6) q column-softmax stats (bf16 q)
  qstat_part<<<dim3(DD / 256, 32, BB), 256, 0, stream>>>(qbuf, pmax, psum);
  qstat_comb<<<dim3(BB * DD / 256), 256, 0, stream>>>(pmax, psum, cmax, crs);
  // 7) softmax-apply + per-head 64x64 matmul -> out_attn (bf16, overwrites kv)
  attn_apply<<<dim3(NN / 128, HH, BB), 256, 0, stream>>>(qbuf, ctx, cmax, crs, oattn);
  // 8) x2 = out_attn @ Wo + bo + x   -> bf16 (overwrites q)
  gemm256<4><<<dim3((unsigned)(nm * (DD / 256))), 512, 0, stream>>>(
      oattn, WoT, bo, x, qbuf, DD, DD, DD, DD, DD / 256);
  short* x2b = qbuf;  // bf16 x2
  // 9) LN_f(x2) -> bf16
  ln_rows_b<<<dim3((unsigned)MR), 256, 0, stream>>>(x2b, ln_f_g, ln_f_b, lnbuf);
  // 10) MLP: h = silu(x2ln @ W1 + b1); out = x2 + h @ W2 + b2
  for (int c0 = 0; c0 < 4096; c0 += CS) {
    gemm256<3><<<dim3((unsigned)(nm * (CS / 256))), 512, 0, stream>>>(
        lnbuf, W1T + (long)c0 * DD, b1 + c0, nullptr, hbuf, CS, DD, DD, DD, CS / 256);
    if (c0 == 0) {
      gemm256<5><<<dim3((unsigned)(nm * (DD / 256))), 512, 0, stream>>>(
          hbuf, W2T + c0, b2, x2b, outp, DD, CS, CS, 4096, DD / 256);
    } else {
      gemm256<1><<<dim3((unsigned)(nm * (DD / 256))), 512, 0, stream>>>(
          hbuf, W2T + c0, nullptr, outp, outp, DD, CS, CS, 4096, DD / 256);
    }
  }
}

// Round 16
// 1259.340 us; speedup vs baseline: 1.0641x; 1.0641x over previous
//
#include <hip/hip_runtime.h>
#include <stdint.h>
#include <stddef.h>

#define BB 8
#define NN 4096
#define MTOK 1024
#define DD 1024
#define HH 16
#define EPSF 1e-6f
static const float SCALE_F = 0.125f; // HD^-0.5, HD=64

typedef __attribute__((ext_vector_type(4))) float f32x4;
typedef __attribute__((ext_vector_type(8))) short bf16x8;

__device__ __forceinline__ short f2bf(float f) {
  union { float f; uint32_t u; } x; x.f = f;
  uint32_t r = (x.u + 0x7fffu + ((x.u >> 16) & 1u)) >> 16;
  return (short)(uint16_t)r;
}
__device__ __forceinline__ float bf2f(short s) {
  union { uint32_t u; float f; } x; x.u = ((uint32_t)(uint16_t)s) << 16;
  return x.f;
}

#if defined(__HIP_DEVICE_COMPILE__) && __has_builtin(__builtin_amdgcn_global_load_lds)
#define USE_GLOAD_LDS 1
#else
#define USE_GLOAD_LDS 0
#endif

#define BAR() __builtin_amdgcn_s_barrier()
#define LGKM0() asm volatile("s_waitcnt lgkmcnt(0)" ::: "memory")
#define LGKM8() asm volatile("s_waitcnt lgkmcnt(8)" ::: "memory")
#if USE_GLOAD_LDS
#define VMW6() asm volatile("s_waitcnt vmcnt(6)" ::: "memory")
#else
#define VMW6() asm volatile("s_waitcnt vmcnt(0) lgkmcnt(0)" ::: "memory")
#endif
#define VMW0() asm volatile("s_waitcnt vmcnt(0)" ::: "memory")

// ---------------------------------------------------------------------------
// 256x256 8-phase bf16 GEMM — round-12/14 best config (m201 schedule).
// EPI: 0 f32 | 1 f32 + f32-resid | 2 bf16 | 3 bf16 silu
//      4 bf16 + f32-resid | 5 f32 + bf16-resid
// ---------------------------------------------------------------------------
__device__ __forceinline__ bf16x8 ldsld(const char* p, int off) {
  return *(const bf16x8*)(p + off);
}
template <int MH>
__device__ __forceinline__ void rdA8(const char* k0, const char* k1, bf16x8 a[4][2]) {
#pragma unroll
  for (int m = 0; m < 4; ++m) {
    a[m][0] = ldsld(k0, MH * 8192 + m * 2048);
    a[m][1] = ldsld(k1, MH * 8192 + m * 2048);
  }
}
template <int NH>
__device__ __forceinline__ void rdB4(const char* k0, const char* k1, bf16x8 b[2][2]) {
#pragma unroll
  for (int n = 0; n < 2; ++n) {
    b[n][0] = ldsld(k0, NH * 16384 + n * 2048);
    b[n][1] = ldsld(k1, NH * 16384 + n * 2048);
  }
}
__device__ __forceinline__ void stgA(char* smc, int base, const short* pg,
                                     int ld, int mh, int k, int w) {
#pragma unroll
  for (int i = 0; i < 2; ++i) {
    const short* src = pg + (long)(mh * 64 + i * 128) * ld + k;
    char* dst = smc + base + i * 16384 + mh * 8192 + w * 1024;
#if USE_GLOAD_LDS
    __builtin_amdgcn_global_load_lds(
        (const __attribute__((address_space(1))) void*)src,
        (__attribute__((address_space(3))) void*)dst, 16, 0, 0);
#else
    *(bf16x8*)(dst + (int)(threadIdx.x & 63) * 16) = *(const bf16x8*)src;
#endif
  }
}
__device__ __forceinline__ void stgB(char* smc, int base, const short* pg,
                                     int ld, int h, int k, int w) {
#pragma unroll
  for (int i = 0; i < 2; ++i) {
    const short* src = pg + (long)(h * 32 + i * 128) * ld + k;
    char* dst = smc + base + h * 16384 + i * 8192 + w * 1024;
#if USE_GLOAD_LDS
    __builtin_amdgcn_global_load_lds(
        (const __attribute__((address_space(1))) void*)src,
        (__attribute__((address_space(3))) void*)dst, 16, 0, 0);
#else
    *(bf16x8*)(dst + (int)(threadIdx.x & 63) * 16) = *(const bf16x8*)src;
#endif
  }
}
template <int MH, int NH>
__device__ __forceinline__ void mq(const bf16x8 a[4][2], const bf16x8 b[2][2],
                                   f32x4 acc[8][4]) {
  __builtin_amdgcn_s_setprio(1);
#pragma unroll
  for (int m = 0; m < 4; ++m)
#pragma unroll
    for (int n = 0; n < 2; ++n) {
      f32x4 c = acc[MH * 4 + m][NH * 2 + n];
      c = __builtin_amdgcn_mfma_f32_16x16x32_bf16(a[m][0], b[n][0], c, 0, 0, 0);
      c = __builtin_amdgcn_mfma_f32_16x16x32_bf16(a[m][1], b[n][1], c, 0, 0, 0);
      acc[MH * 4 + m][NH * 2 + n] = c;
    }
  __builtin_amdgcn_s_setprio(0);
}

template <int EPI>
__global__ __launch_bounds__(512, 2) void gemm256(
    const short* __restrict__ A, const short* __restrict__ BT,
    const float* __restrict__ bias, const void* __restrict__ resid,
    void* __restrict__ outp, int N, int K, int lda, int ldb, int num_n) {
  __shared__ int4 smem4[131072 / 16];
  char* smc = (char*)smem4;
  const int t = threadIdx.x;
  const int w = t >> 6, lane = t & 63;
  const int wr = w >> 2, wc = w & 3;

  // bijective XCD swizzle (m204)
  const int nwg = gridDim.x, orig = blockIdx.x;
  const int q8 = nwg >> 3, r8 = nwg & 7;
  const int xcd = orig & 7, loc = orig >> 3;
  const int wg = (xcd < r8 ? xcd * (q8 + 1) : r8 * (q8 + 1) + (xcd - r8) * q8) + loc;
  // ROW-major tile mapping: consecutive wg (same XCD) share the A panel.
  const int bm = wg / num_n, bn = wg % num_n;

  const int T = K >> 6;

  // swizzled ds_read base pointers (ks=1 = base^64)
  int LA = wr * 16384 + (lane & 15) * 128 + ((lane >> 4) << 4);
  LA ^= ((LA >> 7) & 7) << 4;
  int LB = wc * 4096 + (lane & 15) * 128 + ((lane >> 4) << 4);
  LB ^= ((LB >> 7) & 7) << 4;
  const char* pA0k0 = smc + LA;
  const char* pA0k1 = smc + (LA ^ 64);
  const char* pA1k0 = pA0k0 + 65536;
  const char* pA1k1 = pA0k1 + 65536;
  const char* pB0k0 = smc + 32768 + LB;
  const char* pB0k1 = smc + 32768 + (LB ^ 64);
  const char* pB1k0 = pB0k0 + 65536;
  const char* pB1k1 = pB0k1 + 65536;

  // stage source pointers (pre-swizzled per-thread row/col)
  const int colswz = ((t & 7) ^ ((t >> 3) & 7)) * 8;
  const short* pAg = A + (long)(bm * 256 + (t >> 3)) * lda + colswz;
  const short* pBg =
      BT + (long)(bn * 256 + ((t >> 8) * 64 + ((t >> 3) & 31))) * ldb + colswz;

  f32x4 acc[8][4];
#pragma unroll
  for (int i = 0; i < 8; ++i)
#pragma unroll
    for (int j = 0; j < 4; ++j) acc[i][j] = (f32x4){0.f, 0.f, 0.f, 0.f};

  bf16x8 a[4][2], b0[2][2], b1[2][2];

  // ---- prologue: buf0 <- tile0 (4 halves), buf1 <- tile1 (A0,B0,B1)
  stgA(smc, 0, pAg, lda, 0, 0, w);
  stgB(smc, 32768, pBg, ldb, 0, 0, w);
  stgB(smc, 32768, pBg, ldb, 1, 0, w);
  stgA(smc, 0, pAg, lda, 1, 0, w);
  stgA(smc, 65536, pAg, lda, 0, 64, w);
  stgB(smc, 98304, pBg, ldb, 0, 64, w);
  stgB(smc, 98304, pBg, ldb, 1, 64, w);
  VMW6();
  BAR();

  for (int t2 = 0; t2 < T; t2 += 2) {
    const int k1 = (t2 + 1) * 64;
    const int k2 = (t2 + 2 < T ? t2 + 2 : 0) * 64;
    const int k3 = (t2 + 3 < T ? t2 + 3 : 0) * 64;
    // P1
    rdA8<0>(pA0k0, pA0k1, a);
    rdB4<0>(pB0k0, pB0k1, b0);
    stgA(smc, 65536, pAg, lda, 1, k1, w);
    LGKM8();
    BAR(); LGKM0();
    mq<0, 0>(a, b0, acc);
    BAR();
    // P2
    rdB4<1>(pB0k0, pB0k1, b1);
    stgA(smc, 0, pAg, lda, 0, k2, w);
    BAR(); LGKM0();
    mq<0, 1>(a, b1, acc);
    BAR();
    // P3
    rdA8<1>(pA0k0, pA0k1, a);
    stgB(smc, 32768, pBg, ldb, 0, k2, w);
    BAR(); LGKM0();
    mq<1, 0>(a, b0, acc);
    BAR();
    // P4
    stgB(smc, 32768, pBg, ldb, 1, k2, w);
    VMW6();
    BAR();
    mq<1, 1>(a, b1, acc);
    BAR();
    // P5
    rdA8<0>(pA1k0, pA1k1, a);
    rdB4<0>(pB1k0, pB1k1, b0);
    stgA(smc, 0, pAg, lda, 1, k2, w);
    LGKM8();
    BAR(); LGKM0();
    mq<0, 0>(a, b0, acc);
    BAR();
    // P6
    rdB4<1>(pB1k0, pB1k1, b1);
    stgA(smc, 65536, pAg, lda, 0, k3, w);
    BAR(); LGKM0();
    mq<0, 1>(a, b1, acc);
    BAR();
    // P7
    rdA8<1>(pA1k0, pA1k1, a);
    stgB(smc, 98304, pBg, ldb, 0, k3, w);
    BAR(); LGKM0();
    mq<1, 0>(a, b0, acc);
    BAR();
    // P8
    stgB(smc, 98304, pBg, ldb, 1, k3, w);
    VMW6();
    BAR();
    mq<1, 1>(a, b1, acc);
    BAR();
  }
  VMW0();

  // ---- epilogue ----
  const int r0 = bm * 256 + wr * 128 + ((lane >> 4) << 2);
  const int c0 = bn * 256 + wc * 64 + (lane & 15);
#pragma unroll
  for (int mi = 0; mi < 8; ++mi) {
#pragma unroll
    for (int ni = 0; ni < 4; ++ni) {
      const int col = c0 + ni * 16;
      const float bv = bias ? bias[col] : 0.f;
#pragma unroll
      for (int rr = 0; rr < 4; ++rr) {
        const int row = r0 + mi * 16 + rr;
        const long idx = (long)row * N + col;
        float v = acc[mi][ni][rr] + bv;
        if (EPI == 0) {
          ((float*)outp)[idx] = v;
        } else if (EPI == 1) {
          ((float*)outp)[idx] = v + ((const float*)resid)[idx];
        } else if (EPI == 2) {
          ((short*)outp)[idx] = f2bf(v);
        } else if (EPI == 3) {
          v = v / (1.f + __expf(-v));
          ((short*)outp)[idx] = f2bf(v);
        } else if (EPI == 4) {
          ((short*)outp)[idx] = f2bf(v + ((const float*)resid)[idx]);
        } else {
          ((float*)outp)[idx] = v + bf2f(((const short*)resid)[idx]);
        }
      }
    }
  }
}

// ---------------------------------------------------------------------------
// Row LayerNorm over D=1024, fp32 in -> bf16 out. One block (256 thr) per row.
// ---------------------------------------------------------------------------
__global__ __launch_bounds__(256) void ln_rows(const float* __restrict__ in,
                                               const float* __restrict__ g,
                                               const float* __restrict__ bta,
                                               short* __restrict__ outp) {
  const int row = blockIdx.x;
  const int t = threadIdx.x;
  const float4 v = ((const float4*)(in + (long)row * DD))[t];
  float s = v.x + v.y + v.z + v.w;
  float ss = v.x * v.x + v.y * v.y + v.z * v.z + v.w * v.w;
#pragma unroll
  for (int off = 1; off < 64; off <<= 1) {
    s += __shfl_xor(s, off);
    ss += __shfl_xor(ss, off);
  }
  __shared__ float red[8];
  const int w = t >> 6, lane = t & 63;
  if (lane == 0) { red[w] = s; red[4 + w] = ss; }
  __syncthreads();
  s = red[0] + red[1] + red[2] + red[3];
  ss = red[4] + red[5] + red[6] + red[7];
  const float mu = s * (1.f / DD);
  const float var = ss * (1.f / DD) - mu * mu;
  const float rs = rsqrtf(var + EPSF);
  const float4 gv = ((const float4*)g)[t];
  const float4 bv = ((const float4*)bta)[t];
  short4 o;
  o.x = f2bf((v.x - mu) * rs * gv.x + bv.x);
  o.y = f2bf((v.y - mu) * rs * gv.y + bv.y);
  o.z = f2bf((v.z - mu) * rs * gv.z + bv.z);
  o.w = f2bf((v.w - mu) * rs * gv.w + bv.w);
  ((short4*)(outp + (long)row * DD))[t] = o;
}

// ---------------------------------------------------------------------------
// Row LayerNorm, bf16 in -> bf16 out (for x2).
// ---------------------------------------------------------------------------
__global__ __launch_bounds__(256) void ln_rows_b(const short* __restrict__ in,
                                                 const float* __restrict__ g,
                                                 const float* __restrict__ bta,
                                                 short* __restrict__ outp) {
  const int row = blockIdx.x;
  const int t = threadIdx.x;
  const short4 v4 = ((const short4*)(in + (long)row * DD))[t];
  const float v0 = bf2f(v4.x), v1 = bf2f(v4.y), v2 = bf2f(v4.z), v3 = bf2f(v4.w);
  float s = v0 + v1 + v2 + v3;
  float ss = v0 * v0 + v1 * v1 + v2 * v2 + v3 * v3;
#pragma unroll
  for (int off = 1; off < 64; off <<= 1) {
    s += __shfl_xor(s, off);
    ss += __shfl_xor(ss, off);
  }
  __shared__ float red[8];
  const int w = t >> 6, lane = t & 63;
  if (lane == 0) { red[w] = s; red[4 + w] = ss; }
  __syncthreads();
  s = red[0] + red[1] + red[2] + red[3];
  ss = red[4] + red[5] + red[6] + red[7];
  const float mu = s * (1.f / DD);
  const float var = ss * (1.f / DD) - mu * mu;
  const float rs = rsqrtf(var + EPSF);
  const float4 gv = ((const float4*)g)[t];
  const float4 bv = ((const float4*)bta)[t];
  short4 o;
  o.x = f2bf((v0 - mu) * rs * gv.x + bv.x);
  o.y = f2bf((v1 - mu) * rs * gv.y + bv.y);
  o.z = f2bf((v2 - mu) * rs * gv.z + bv.z);
  o.w = f2bf((v3 - mu) * rs * gv.w + bv.w);
  ((short4*)(outp + (long)row * DD))[t] = o;
}

// ---------------------------------------------------------------------------
// Transpose + fp32->bf16 convert: W[K][N] -> WT[N][K]. 64x64 tiles.
// ---------------------------------------------------------------------------
__global__ __launch_bounds__(256) void tconv(const float* __restrict__ W,
                                             short* __restrict__ WT, int K, int N) {
  __shared__ float tile[64][65];
  const int k0 = blockIdx.x * 64, n0 = blockIdx.y * 64;
  const int t = threadIdx.x;
  const int tr = t >> 6, tc = t & 63;
#pragma unroll
  for (int i = 0; i < 64; i += 4)
    tile[i + tr][tc] = W[(long)(k0 + i + tr) * N + n0 + tc];
  __syncthreads();
#pragma unroll
  for (int i = 0; i < 64; i += 4)
    WT[(long)(n0 + i + tr) * K + k0 + tc] = f2bf(tile[tc][i + tr]);
}

// ---------------------------------------------------------------------------
// ctx[b,h,d,e] = sum_m softmax_d(k[b,m,h,:])[d] * v[b,m,h,e].
// ---------------------------------------------------------------------------
__global__ __launch_bounds__(256) void ctx_kernel(const short* __restrict__ kv,
                                                  float* __restrict__ ctx) {
  const int bh = blockIdx.x;
  const int b = bh >> 4, h = bh & 15;
  const int t = threadIdx.x, g = t >> 6, lane = t & 63;
  __shared__ float ksm[4][64];
  __shared__ float vsm[4][64];
  float acc[16];
#pragma unroll
  for (int j = 0; j < 16; ++j) acc[j] = 0.f;
  const int d = t & 63;
  const int e0 = (t >> 6) * 16;
  const short* base = kv + (long)b * MTOK * 2048 + h * 64;
  for (int m0 = 0; m0 < MTOK; m0 += 4) {
    const long moff = (long)(m0 + g) * 2048;
    float kval = bf2f(base[moff + lane]);
    float vval = bf2f(base[moff + 1024 + lane]);
    float mx = kval;
#pragma unroll
    for (int off = 1; off < 64; off <<= 1) mx = fmaxf(mx, __shfl_xor(mx, off));
    float e = __expf(kval - mx);
    float sm = e;
#pragma unroll
    for (int off = 1; off < 64; off <<= 1) sm += __shfl_xor(sm, off);
    ksm[g][lane] = e / sm;
    vsm[g][lane] = vval;
    __syncthreads();
#pragma unroll
    for (int mm = 0; mm < 4; ++mm) {
      const float kd = ksm[mm][d];
#pragma unroll
      for (int j = 0; j < 16; ++j) acc[j] = fmaf(kd, vsm[mm][e0 + j], acc[j]);
    }
    __syncthreads();
  }
  float* cp = ctx + ((long)bh * 64 + d) * 64 + e0;
#pragma unroll
  for (int j = 0; j < 16; ++j) cp[j] = acc[j];
}

// ---------------------------------------------------------------------------
// Column softmax stats for q (bf16), softmax over the N axis per (b, column).
// ---------------------------------------------------------------------------
__global__ __launch_bounds__(256) void qstat_part(const short* __restrict__ q,
                                                  float* __restrict__ pmax,
                                                  float* __restrict__ psum) {
  const int c = blockIdx.x * 256 + threadIdx.x;
  const int b = blockIdx.z, ch = blockIdx.y;
  const short* qp = q + ((long)b * NN + ch * 128) * DD + c;
  float mx = -1e30f, sm = 0.f;
  for (int r = 0; r < 128; ++r) {
    const float xv = bf2f(qp[(long)r * DD]);
    const float nm = fmaxf(mx, xv);
    sm = sm * __expf(mx - nm) + __expf(xv - nm);
    mx = nm;
  }
  const long idx = ((long)b * DD + c) * 32 + ch;
  pmax[idx] = mx;
  psum[idx] = sm;
}

__global__ __launch_bounds__(256) void qstat_comb(const float* __restrict__ pmax,
                                                  const float* __restrict__ psum,
                                                  float* __restrict__ cmax,
                                                  float* __restrict__ crs) {
  const int i = blockIdx.x * 256 + threadIdx.x;  // b*1024 + c
  const float* pm = pmax + (long)i * 32;
  const float* ps = psum + (long)i * 32;
  float mx = -1e30f;
#pragma unroll
  for (int ch = 0; ch < 32; ++ch) mx = fmaxf(mx, pm[ch]);
  float sm = 0.f;
#pragma unroll
  for (int ch = 0; ch < 32; ++ch) sm += ps[ch] * __expf(pm[ch] - mx);
  cmax[i] = mx;
  crs[i] = SCALE_F / sm;
}

// ---------------------------------------------------------------------------
// Fused: q_soft = exp(q-cmax)*crs (includes SCALE), out = q_soft @ ctx[b,h].
// q is bf16.
// ---------------------------------------------------------------------------
__global__ __launch_bounds__(256) void attn_apply(const short* __restrict__ q,
                                                  const float* __restrict__ ctx,
                                                  const float* __restrict__ cmax,
                                                  const float* __restrict__ crs,
                                                  short* __restrict__ outa) {
  const int b = blockIdx.z, h = blockIdx.y, n0 = blockIdx.x * 128;
  const int t = threadIdx.x, g = t >> 6, lane = t & 63;
  __shared__ float ctx_l[4096];
  __shared__ float cm[64], cs[64];
  __shared__ float qsm[4][64];
  const float* cp = ctx + (long)(b * HH + h) * 4096;
  for (int i = t; i < 4096; i += 256) ctx_l[i] = cp[i];
  if (t < 64) {
    cm[t] = cmax[(long)b * DD + h * 64 + t];
    cs[t] = crs[(long)b * DD + h * 64 + t];
  }
  __syncthreads();
  for (int i = 0; i < 32; ++i) {
    const int n = n0 + i * 4 + g;
    const long off = ((long)b * NN + n) * DD + h * 64;
    const float qv = bf2f(q[off + lane]);
    const float qs = __expf(qv - cm[lane]) * cs[lane];
    qsm[g][lane] = qs;  // same-wave LDS, no barrier needed
    float o = 0.f;
#pragma unroll
    for (int dd = 0; dd < 64; ++dd) o = fmaf(qsm[g][dd], ctx_l[dd * 64 + lane], o);
    outa[off + lane] = f2bf(o);
  }
}

// ---------------------------------------------------------------------------
extern "C" void kernel_launch(void* const* d_in, const int* in_sizes, int n_in,
                              void* d_out, int out_size, void* d_ws, size_t ws_size,
                              hipStream_t stream) {
  (void)in_sizes; (void)n_in; (void)out_size;
  const float* x      = (const float*)d_in[0];
  const float* wav    = (const float*)d_in[1];
  const float* ln_q_g = (const float*)d_in[2];
  const float* ln_q_b = (const float*)d_in[3];
  const float* Wq     = (const float*)d_in[4];
  const float* bq     = (const float*)d_in[5];
  const float* ln_kv_g= (const float*)d_in[6];
  const float* ln_kv_b= (const float*)d_in[7];
  const float* Wkv    = (const float*)d_in[8];
  const float* bkv    = (const float*)d_in[9];
  const float* Wo     = (const float*)d_in[10];
  const float* bo     = (const float*)d_in[11];
  const float* ln_f_g = (const float*)d_in[12];
  const float* ln_f_b = (const float*)d_in[13];
  const float* W1     = (const float*)d_in[14];
  const float* b1     = (const float*)d_in[15];
  const float* W2     = (const float*)d_in[16];
  const float* b2     = (const float*)d_in[17];
  float* outp = (float*)d_out;
  char* ws = (char*)d_ws;

  const long MR = (long)BB * NN;    // 32768 rows
  const long MKV = (long)BB * MTOK; // 8192 rows

  size_t off = 0;
  auto bump = [&](size_t bytes) {
    size_t o = off;
    off += (bytes + 255) & ~(size_t)255;
    return o;
  };
  short* WqT  = (short*)(ws + bump((size_t)DD * DD * 2));
  short* WkvT = (short*)(ws + bump((size_t)2048 * DD * 2));
  short* WoT  = (short*)(ws + bump((size_t)DD * DD * 2));
  short* W1T  = (short*)(ws + bump((size_t)4096 * DD * 2));
  short* W2T  = (short*)(ws + bump((size_t)DD * 4096 * 2));
  short* qbuf = (short*)(ws + bump((size_t)MR * DD * 2));   // q bf16, later x2 bf16
  short* lnbuf= (short*)(ws + bump((size_t)MR * DD * 2));   // xq_ln, later x2_ln
  float* ctx  = (float*)(ws + bump((size_t)BB * HH * 64 * 64 * 4));
  float* pmax = (float*)(ws + bump((size_t)BB * DD * 32 * 4));
  float* psum = (float*)(ws + bump((size_t)BB * DD * 32 * 4));
  float* cmax = (float*)(ws + bump((size_t)BB * DD * 4));
  float* crs  = (float*)(ws + bump((size_t)BB * DD * 4));
  const size_t dyn0 = off;
  short* wvln  = (short*)(ws + dyn0);
  short* kvbuf = (short*)(ws + dyn0 + (size_t)MKV * DD * 2);
  short* oattn = (short*)(ws + dyn0);  // reuses wvln+kv region (dead by then)
  short* hbuf  = (short*)(ws + dyn0);  // MLP phase (oattn dead by then)

  size_t avail = ws_size > dyn0 ? ws_size - dyn0 : 0;
  int CS = 4096;
  while (CS > 256 && (size_t)MR * CS * 2 > avail) CS >>= 1;

  const int nm = (int)(MR / 256);    // 128
  const int nmkv = (int)(MKV / 256); // 32

  // 1) weight convert+transpose to bf16 [N][K]
  tconv<<<dim3(DD / 64, DD / 64), 256, 0, stream>>>(Wq, WqT, DD, DD);
  tconv<<<dim3(DD / 64, 2048 / 64), 256, 0, stream>>>(Wkv, WkvT, DD, 2048);
  tconv<<<dim3(DD / 64, DD / 64), 256, 0, stream>>>(Wo, WoT, DD, DD);
  tconv<<<dim3(DD / 64, 4096 / 64), 256, 0, stream>>>(W1, W1T, DD, 4096);
  tconv<<<dim3(4096 / 64, DD / 64), 256, 0, stream>>>(W2, W2T, 4096, DD);

  // 2) LayerNorms -> bf16
  ln_rows<<<dim3((unsigned)MR), 256, 0, stream>>>(x, ln_q_g, ln_q_b, lnbuf);
  ln_rows<<<dim3((unsigned)MKV), 256, 0, stream>>>(wav, ln_kv_g, ln_kv_b, wvln);

  // 3) q = LN(x) @ Wq + bq   -> bf16
  gemm256<2><<<dim3((unsigned)(nm * (DD / 256))), 512, 0, stream>>>(
      lnbuf, WqT, bq, nullptr, qbuf, DD, DD, DD, DD, DD / 256);
  // 4) kv = LN(wav) @ Wkv + bkv  (bf16 out)
  gemm256<2><<<dim3((unsigned)(nmkv * (2048 / 256))), 512, 0, stream>>>(
      wvln, WkvT, bkv, nullptr, kvbuf, 2048, DD, DD, DD, 2048 / 256);
  // 5) context per (b,h)
  ctx_kernel<<<dim3(BB * HH), 256, 0, stream>>>(kvbuf, ctx);
  // 6) q column-softmax stats (bf16 q)
  qstat_part<<<dim3(DD / 256, 32, BB), 256, 0, stream>>>(qbuf, pmax, psum);
  qstat_comb<<<dim3(BB * DD / 256), 256, 0, stream>>>(pmax, psum, cmax, crs);
  // 7) softmax-apply + per-head 64x64 matmul -> out_attn (bf16, overwrites kv)
  attn_apply<<<dim3(NN / 128, HH, BB), 256, 0, stream>>>(qbuf, ctx, cmax, crs, oattn);
  // 8) x2 = out_attn @ Wo + bo + x   -> bf16 (overwrites q)
  gemm256<4><<<dim3((unsigned)(nm * (DD / 256))), 512, 0, stream>>>(
      oattn, WoT, bo, x, qbuf, DD, DD, DD, DD, DD / 256);
  short* x2b = qbuf;  // bf16 x2
  // 9) LN_f(x2) -> bf16
  ln_rows_b<<<dim3((unsigned)MR), 256, 0, stream>>>(x2b, ln_f_g, ln_f_b, lnbuf);
  // 10) MLP: h = silu(x2ln @ W1 + b1); out = x2 + h @ W2 + b2
  for (int c0 = 0; c0 < 4096; c0 += CS) {
    gemm256<3><<<dim3((unsigned)(nm * (CS / 256))), 512, 0, stream>>>(
        lnbuf, W1T + (long)c0 * DD, b1 + c0, nullptr, hbuf, CS, DD, DD, DD, CS / 256);
    if (c0 == 0) {
      gemm256<5><<<dim3((unsigned)(nm * (DD / 256))), 512, 0, stream>>>(
          hbuf, W2T + c0, b2, x2b, outp, DD, CS, CS, 4096, DD / 256);
    } else {
      gemm256<1><<<dim3((unsigned)(nm * (DD / 256))), 512, 0, stream>>>(
          hbuf, W2T + c0, nullptr, outp, outp, DD, CS, CS, 4096, DD / 256);
    }
  }
}